// Round 1
// baseline (1287.328 us; speedup 1.0000x reference)
//
#include <hip/hip_runtime.h>
#include <math.h>

#define N 8192
#define IN_F 256
#define OUT_F 128
#define ALPHA 0.2f

#define TI 32          // rows per block in attention kernel
#define NJ 128         // j-chunk
#define NC (N / NJ)    // 64 chunks

// ---------------- Kernel 1: Wh = h @ W ----------------
__global__ __launch_bounds__(256) void k_wh(const float* __restrict__ h,
                                            const float* __restrict__ W,
                                            float* __restrict__ Wh) {
    __shared__ float hs[TI][IN_F];          // 32 KB
    __shared__ float part[OUT_F][TI + 1];   // 16.5 KB
    const int t = threadIdx.x;
    const int f = t & 127;
    const int g = t >> 7;                   // k-half
    const int i0 = blockIdx.x * TI;

    for (int idx = t; idx < TI * IN_F; idx += 256)
        hs[idx >> 8][idx & 255] = h[i0 * IN_F + idx];
    __syncthreads();

    float acc[TI];
#pragma unroll
    for (int r = 0; r < TI; ++r) acc[r] = 0.f;

    const int kbase = g * 128;
    for (int k0 = 0; k0 < 128; k0 += 8) {
        float wreg[8];
#pragma unroll
        for (int kk = 0; kk < 8; ++kk) wreg[kk] = W[(kbase + k0 + kk) * OUT_F + f];
#pragma unroll
        for (int r = 0; r < TI; ++r) {
            float s = acc[r];
#pragma unroll
            for (int kk = 0; kk < 8; ++kk) s += hs[r][kbase + k0 + kk] * wreg[kk];
            acc[r] = s;
        }
    }
    if (g == 1) {
#pragma unroll
        for (int r = 0; r < TI; ++r) part[f][r] = acc[r];
    }
    __syncthreads();
    if (g == 0) {
#pragma unroll
        for (int r = 0; r < TI; ++r) Wh[(i0 + r) * OUT_F + f] = acc[r] + part[f][r];
    }
}

// ---------------- Kernel 2: src = Wh@a1, dst = Wh@a2 ----------------
__global__ __launch_bounds__(256) void k_srcdst(const float* __restrict__ Wh,
                                                const float* __restrict__ a,
                                                float* __restrict__ src,
                                                float* __restrict__ dst) {
    const int t = threadIdx.x;
    const int lane = t & 63;
    const int wv = t >> 6;
    const int i = blockIdx.x * 4 + wv;
    float w0 = Wh[i * OUT_F + lane];
    float w1 = Wh[i * OUT_F + 64 + lane];
    float s = w0 * a[lane] + w1 * a[64 + lane];
    float d = w0 * a[128 + lane] + w1 * a[192 + lane];
#pragma unroll
    for (int off = 32; off > 0; off >>= 1) {
        s += __shfl_down(s, off);
        d += __shfl_down(d, off);
    }
    if (lane == 0) { src[i] = s; dst[i] = d; }
}

// ---------------- Kernel 3: fused masked-softmax attention @ Wh + ELU ----------------
// One block = 32 output rows. Single pass over adj (read exactly once).
// Softmax via fixed per-row shift c_i = |src_i|+4 (safe: |e| <~ 5), normalize at end.
__global__ __launch_bounds__(512) void k_attn(const int* __restrict__ adj,
                                              const float* __restrict__ Wh,
                                              const float* __restrict__ src,
                                              const float* __restrict__ dst,
                                              float* __restrict__ out) {
    __shared__ float wt[2][NJ][36];          // 36.9 KB, stride 36 floats = 144 B (16B aligned rows)
    __shared__ float accbuf[OUT_F][TI + 1];  // 16.9 KB
    __shared__ float lredbuf[8][8];
    __shared__ float lfin[TI];

    const int t = threadIdx.x;
    const int i0 = blockIdx.x * TI;
    // step-1 (w-tile) identity
    const int jj1 = t & 127;
    const int rq = t >> 7;       // 0..3
    const int r8 = rq * 8;
    // step-2 (accumulate) identity
    const int f = t & 127;
    const int g = t >> 7;        // jj quarter

    float sreg[8], creg[8];
#pragma unroll
    for (int k = 0; k < 8; ++k) {
        float s = src[i0 + r8 + k];
        sreg[k] = s;
        creg[k] = fabsf(s) + 4.0f;
    }
    float lp[8];
#pragma unroll
    for (int k = 0; k < 8; ++k) lp[k] = 0.f;
    float acc[TI];
#pragma unroll
    for (int r = 0; r < TI; ++r) acc[r] = 0.f;

    // prologue: stage chunk 0 into wt[0]
    {
        float dv = dst[jj1];
        float w[8];
#pragma unroll
        for (int k = 0; k < 8; ++k) {
            int av = adj[(i0 + r8 + k) * N + jj1];
            float e = sreg[k] + dv;
            float lk = e > 0.f ? e : ALPHA * e;
            float wv = av ? __expf(lk - creg[k]) : 0.f;
            lp[k] += wv;
            w[k] = wv;
        }
        float4* o = (float4*)&wt[0][jj1][r8];
        o[0] = make_float4(w[0], w[1], w[2], w[3]);
        o[1] = make_float4(w[4], w[5], w[6], w[7]);
    }
    __syncthreads();

    for (int c = 0; c < NC; ++c) {
        const int buf = c & 1;
        const bool more = (c + 1 < NC);
        int apf[8];
        float dpf = 0.f;
        if (more) {  // prefetch next chunk's adj/dst (hide HBM latency under fmacs)
            const int j = (c + 1) * NJ + jj1;
            dpf = dst[j];
#pragma unroll
            for (int k = 0; k < 8; ++k) apf[k] = adj[(i0 + r8 + k) * N + j];
        }
        // accumulate this chunk: acc[r] += wt[jj][r] * Wh[j][f]
        const int jbase = c * NJ;
#pragma unroll 8
        for (int u = 0; u < 32; ++u) {
            const int jj = g * 32 + u;
            float whv = Wh[(jbase + jj) * OUT_F + f];
            const float4* wrow = (const float4*)&wt[buf][jj][0];
#pragma unroll
            for (int q = 0; q < 8; ++q) {
                float4 wv = wrow[q];
                acc[4 * q + 0] += wv.x * whv;
                acc[4 * q + 1] += wv.y * whv;
                acc[4 * q + 2] += wv.z * whv;
                acc[4 * q + 3] += wv.w * whv;
            }
        }
        if (more) {  // compute + store next w-tile
            float w[8];
#pragma unroll
            for (int k = 0; k < 8; ++k) {
                float e = sreg[k] + dpf;
                float lk = e > 0.f ? e : ALPHA * e;
                float wv = apf[k] ? __expf(lk - creg[k]) : 0.f;
                lp[k] += wv;
                w[k] = wv;
            }
            float4* o = (float4*)&wt[buf ^ 1][jj1][r8];
            o[0] = make_float4(w[0], w[1], w[2], w[3]);
            o[1] = make_float4(w[4], w[5], w[6], w[7]);
        }
        __syncthreads();  // single barrier per chunk (double-buffered wt)
    }

    // reduce lp across the 128 threads (2 waves) sharing each r-group
    const int lane = t & 63;
    const int wvi = t >> 6;  // 0..7
#pragma unroll
    for (int k = 0; k < 8; ++k) {
        float v = lp[k];
#pragma unroll
        for (int off = 32; off > 0; off >>= 1) v += __shfl_down(v, off);
        if (lane == 0) lredbuf[wvi][k] = v;
    }
    __syncthreads();
    if (t < TI) {
        int q = t >> 3, k = t & 7;
        lfin[t] = lredbuf[2 * q][k] + lredbuf[2 * q + 1][k];
    }
    // combine partial accumulators across the 4 jj-quarters
    if (g == 0) {
#pragma unroll
        for (int r = 0; r < TI; ++r) accbuf[f][r] = acc[r];
    }
    __syncthreads();
    if (g == 1) {
#pragma unroll
        for (int r = 0; r < TI; ++r) accbuf[f][r] += acc[r];
    }
    __syncthreads();
    if (g == 2) {
#pragma unroll
        for (int r = 0; r < TI; ++r) accbuf[f][r] += acc[r];
    }
    __syncthreads();
    if (g == 3) {
#pragma unroll
        for (int r = 0; r < TI; ++r) accbuf[f][r] += acc[r];
    }
    __syncthreads();

    // epilogue: normalize, ELU, store
    {
        const int q = t >> 7;
#pragma unroll
        for (int k = 0; k < 8; ++k) {
            int r = q * 8 + k;
            float hp = accbuf[f][r] / lfin[r];
            float res = hp > 0.f ? hp : expm1f(hp);
            out[(i0 + r) * OUT_F + f] = res;
        }
    }
}

extern "C" void kernel_launch(void* const* d_in, const int* in_sizes, int n_in,
                              void* d_out, int out_size, void* d_ws, size_t ws_size,
                              hipStream_t stream) {
    const float* h   = (const float*)d_in[0];
    const int*   adj = (const int*)d_in[1];
    const float* W   = (const float*)d_in[2];
    const float* a   = (const float*)d_in[3];
    float* out = (float*)d_out;

    float* Wh  = (float*)d_ws;            // N*OUT_F floats = 4 MB
    float* src = Wh + (size_t)N * OUT_F;  // N floats
    float* dst = src + N;                 // N floats

    k_wh<<<N / TI, 256, 0, stream>>>(h, W, Wh);
    k_srcdst<<<N / 4, 256, 0, stream>>>(Wh, a, src, dst);
    k_attn<<<N / TI, 512, 0, stream>>>(adj, Wh, src, dst, out);
}

// Round 2
// 417.699 us; speedup vs baseline: 3.0820x; 3.0820x over previous
//
#include <hip/hip_runtime.h>
#include <math.h>

#define N 8192
#define IN_F 256
#define OUT_F 128
#define ALPHA 0.2f

typedef _Float16 f16;
typedef __attribute__((ext_vector_type(4))) float f32x4;
typedef __attribute__((ext_vector_type(8))) _Float16 f16x8;
typedef __attribute__((ext_vector_type(4))) _Float16 f16x4;

// ---------------- Kernel 0: WT[f][k] = (f16) W[k][f] ----------------
__global__ __launch_bounds__(256) void k_prep(const float* __restrict__ W,
                                              f16* __restrict__ WT) {
    int idx = blockIdx.x * 256 + threadIdx.x;   // 128*256 = 32768 elements
    int f = idx >> 8;
    int k = idx & 255;
    WT[idx] = (f16)W[k * OUT_F + f];
}

// ---------------- Kernel 1: Wh = h@W via MFMA; emit WhT(f16), src, dst ----------------
// Block: 256 threads (4 waves), 32 rows. Wave wv handles f-slice [32wv, 32wv+32).
#define HS 280   // f16 row stride for hA: 560 B = 140 dw === 12 (mod 32) -> conflict-optimal b128
__global__ __launch_bounds__(256) void k_wh(const float* __restrict__ h,
                                            const f16* __restrict__ WT,   // [128][256]
                                            const float* __restrict__ a,
                                            f16* __restrict__ WhT,        // [128][8192]
                                            float* __restrict__ src,
                                            float* __restrict__ dst) {
    __shared__ __align__(16) f16 hA[32][HS];       // 17.9 KB
    __shared__ __align__(16) f16 outT[128][40];    // [col][row], 80 B rows, 10 KB
    __shared__ float sred[4][32], dred[4][32];

    const int t = threadIdx.x;
    const int i0 = blockIdx.x * 32;
    const int wv = t >> 6, l = t & 63, ln = l & 15, lq = l >> 4;

    // stage h tile (32 x 256 fp32) -> f16 LDS
    {
        const float4* hg = (const float4*)(h + (size_t)i0 * IN_F);
#pragma unroll
        for (int it = 0; it < 8; ++it) {
            int idx = t + it * 256;        // float4 index, 2048 total
            int r = idx >> 6;
            int c4 = (idx & 63) * 4;
            float4 v = hg[idx];
            f16x4 p = { (f16)v.x, (f16)v.y, (f16)v.z, (f16)v.w };
            *(f16x4*)&hA[r][c4] = p;
        }
    }
    __syncthreads();

    f32x4 acc00 = {0.f,0.f,0.f,0.f}, acc01 = {0.f,0.f,0.f,0.f};
    f32x4 acc10 = {0.f,0.f,0.f,0.f}, acc11 = {0.f,0.f,0.f,0.f};
    const int f0 = 32 * wv;

#pragma unroll
    for (int ks = 0; ks < 8; ++ks) {
        const int k0 = 32 * ks + 8 * lq;
        f16x8 a0 = *(const f16x8*)&hA[ln][k0];
        f16x8 a1 = *(const f16x8*)&hA[16 + ln][k0];
        f16x8 b0 = *(const f16x8*)(WT + (size_t)(f0 + ln) * IN_F + k0);
        f16x8 b1 = *(const f16x8*)(WT + (size_t)(f0 + 16 + ln) * IN_F + k0);
        acc00 = __builtin_amdgcn_mfma_f32_16x16x32_f16(a0, b0, acc00, 0, 0, 0);
        acc01 = __builtin_amdgcn_mfma_f32_16x16x32_f16(a0, b1, acc01, 0, 0, 0);
        acc10 = __builtin_amdgcn_mfma_f32_16x16x32_f16(a1, b0, acc10, 0, 0, 0);
        acc11 = __builtin_amdgcn_mfma_f32_16x16x32_f16(a1, b1, acc11, 0, 0, 0);
    }

    // epilogue: per-lane src/dst partials + outT staging
    const float a1c0 = a[f0 + ln],      a2c0 = a[128 + f0 + ln];
    const float a1c1 = a[f0 + 16 + ln], a2c1 = a[128 + f0 + 16 + ln];
    float sp[8], dp[8];
#pragma unroll
    for (int i = 0; i < 8; ++i) { sp[i] = 0.f; dp[i] = 0.f; }

#pragma unroll
    for (int hh = 0; hh < 2; ++hh) {
        f32x4 v0 = hh ? acc10 : acc00;   // ft=0
        f32x4 v1 = hh ? acc11 : acc01;   // ft=1
        f16x4 p0, p1;
#pragma unroll
        for (int rg = 0; rg < 4; ++rg) {
            sp[hh * 4 + rg] += v0[rg] * a1c0 + v1[rg] * a1c1;
            dp[hh * 4 + rg] += v0[rg] * a2c0 + v1[rg] * a2c1;
            p0[rg] = (f16)v0[rg];
            p1[rg] = (f16)v1[rg];
        }
        *(f16x4*)&outT[f0 + ln][16 * hh + 4 * lq] = p0;
        *(f16x4*)&outT[f0 + 16 + ln][16 * hh + 4 * lq] = p1;
    }
    // reduce over ln (16 lanes sharing lq)
#pragma unroll
    for (int i = 0; i < 8; ++i) {
        float s = sp[i], d = dp[i];
        s += __shfl_down(s, 8, 16); d += __shfl_down(d, 8, 16);
        s += __shfl_down(s, 4, 16); d += __shfl_down(d, 4, 16);
        s += __shfl_down(s, 2, 16); d += __shfl_down(d, 2, 16);
        s += __shfl_down(s, 1, 16); d += __shfl_down(d, 1, 16);
        if (ln == 0) {
            int row = 16 * (i >> 2) + 4 * lq + (i & 3);
            sred[wv][row] = s;
            dred[wv][row] = d;
        }
    }
    __syncthreads();
    if (t < 32) {
        src[i0 + t] = sred[0][t] + sred[1][t] + sred[2][t] + sred[3][t];
        dst[i0 + t] = dred[0][t] + dred[1][t] + dred[2][t] + dred[3][t];
    }
    // write WhT[col][i0..i0+31]
    {
        const int col = t & 127, g = t >> 7;
        f16x8 q0 = *(const f16x8*)&outT[col][16 * g];
        f16x8 q1 = *(const f16x8*)&outT[col][16 * g + 8];
        *(f16x8*)(WhT + (size_t)col * N + i0 + 16 * g) = q0;
        *(f16x8*)(WhT + (size_t)col * N + i0 + 16 * g + 8) = q1;
    }
}

// ---------------- Kernel 2: fused masked-softmax attention @ Wh + ELU ----------------
// Block: 512 threads (8 waves), 32 rows. Producer thread t: row pr=t>>4, j-octet pm=t&15.
// Consumer wave wv=t>>6: f-slice [16wv,16wv+16), two 16-row C tiles.
#define TI 32
#define NJ 128
#define NC (N / NJ)
#define WSTRIDE 152   // f16; 304 B = 76 dw === 12 (mod 32) -> conflict-optimal b128
__global__ __launch_bounds__(512) void k_attn(const int* __restrict__ adj,
                                              const f16* __restrict__ WhT,
                                              const float* __restrict__ src,
                                              const float* __restrict__ dst,
                                              float* __restrict__ out) {
    __shared__ __align__(16) f16 wA[2][TI][WSTRIDE];   // 19456 B
    __shared__ float lfin[TI];

    const int t = threadIdx.x;
    const int i0 = blockIdx.x * TI;
    const int pr = t >> 4;          // 0..31
    const int pm = t & 15;          // 0..15
    const int wv = t >> 6;          // 0..7
    const int l = t & 63, ln = l & 15, lq = l >> 4;

    const float my_src = src[i0 + pr];
    const float cshift = fabsf(my_src) + 4.0f;
    float lp = 0.f;
    f32x4 accv0 = {0.f,0.f,0.f,0.f}, accv1 = {0.f,0.f,0.f,0.f};

    const int* arow = adj + (size_t)(i0 + pr) * N;
    const f16* Bb = WhT + (size_t)(16 * wv + ln) * N + 8 * lq;

    int4 aA0, aB0, aA1, aB1;
    float4 dA0, dB0, dA1, dB1;

    auto issue = [&](int c, int4& xA, int4& xB, float4& xdA, float4& xdB) {
        const int j0 = c * NJ + 8 * pm;
        xA = *(const int4*)(arow + j0);
        xB = *(const int4*)(arow + j0 + 4);
        xdA = *(const float4*)(dst + j0);
        xdB = *(const float4*)(dst + j0 + 4);
    };
    auto produce = [&](int c, const int4& xA, const int4& xB,
                       const float4& xdA, const float4& xdB) {
        float w[8];
        const int*   av = (const int*)&xA;     // [0..3] then xB
        const int*   bv = (const int*)&xB;
        const float* df = (const float*)&xdA;
        const float* ef = (const float*)&xdB;
#pragma unroll
        for (int k = 0; k < 4; ++k) {
            float e = my_src + df[k];
            float lk = e > 0.f ? e : ALPHA * e;
            w[k] = av[k] ? __expf(lk - cshift) : 0.f;
        }
#pragma unroll
        for (int k = 0; k < 4; ++k) {
            float e = my_src + ef[k];
            float lk = e > 0.f ? e : ALPHA * e;
            w[4 + k] = bv[k] ? __expf(lk - cshift) : 0.f;
        }
        f16x8 wp;
#pragma unroll
        for (int k = 0; k < 8; ++k) { lp += w[k]; wp[k] = (f16)w[k]; }
        *(f16x8*)&wA[c & 1][pr][8 * pm] = wp;
    };
    auto mpass = [&](int c) {
        const f16* wb = &wA[c & 1][0][0];
        const f16* bp = Bb + c * NJ;
#pragma unroll
        for (int ks = 0; ks < 4; ++ks) {
            const int k0 = 32 * ks;
            f16x8 bf = *(const f16x8*)(bp + k0);
            f16x8 a0 = *(const f16x8*)(wb + ln * WSTRIDE + k0 + 8 * lq);
            f16x8 a1 = *(const f16x8*)(wb + (16 + ln) * WSTRIDE + k0 + 8 * lq);
            accv0 = __builtin_amdgcn_mfma_f32_16x16x32_f16(a0, bf, accv0, 0, 0, 0);
            accv1 = __builtin_amdgcn_mfma_f32_16x16x32_f16(a1, bf, accv1, 0, 0, 0);
        }
    };

    // prologue: w0 (blocking), then chunk-1 loads in flight
    issue(0, aA0, aB0, dA0, dB0);
    produce(0, aA0, aB0, dA0, dB0);
    issue(1, aA1, aB1, dA1, dB1);
    __syncthreads();

    for (int cc = 0; cc < NC; cc += 2) {
        // chunk cc (even): prefetch cc+2 into slot0, mfma buf0, produce cc+1 from slot1
        if (cc + 2 < NC) issue(cc + 2, aA0, aB0, dA0, dB0);
        mpass(cc);
        produce(cc + 1, aA1, aB1, dA1, dB1);
        __syncthreads();
        // chunk cc+1 (odd): prefetch cc+3 into slot1, mfma buf1, produce cc+2 from slot0
        if (cc + 3 < NC) issue(cc + 3, aA1, aB1, dA1, dB1);
        mpass(cc + 1);
        if (cc + 2 < NC) produce(cc + 2, aA0, aB0, dA0, dB0);
        __syncthreads();
    }

    // softmax denominator: reduce lp over the 16 pm-lanes of each row
    {
        float v = lp;
        v += __shfl_down(v, 8, 16);
        v += __shfl_down(v, 4, 16);
        v += __shfl_down(v, 2, 16);
        v += __shfl_down(v, 1, 16);
        if (pm == 0) lfin[pr] = v;
    }
    __syncthreads();

    // epilogue: normalize, ELU, store (C layout: col=ln, row=4*lq+reg per 16-tile)
#pragma unroll
    for (int hh = 0; hh < 2; ++hh) {
        f32x4 av = hh ? accv1 : accv0;
#pragma unroll
        for (int rg = 0; rg < 4; ++rg) {
            const int row = 16 * hh + 4 * lq + rg;
            float hp = av[rg] / lfin[row];
            float res = hp > 0.f ? hp : expm1f(hp);
            out[(size_t)(i0 + row) * OUT_F + 16 * wv + ln] = res;
        }
    }
}

extern "C" void kernel_launch(void* const* d_in, const int* in_sizes, int n_in,
                              void* d_out, int out_size, void* d_ws, size_t ws_size,
                              hipStream_t stream) {
    const float* h   = (const float*)d_in[0];
    const int*   adj = (const int*)d_in[1];
    const float* W   = (const float*)d_in[2];
    const float* a   = (const float*)d_in[3];
    float* out = (float*)d_out;

    f16*   WT  = (f16*)d_ws;                         // 128*256*2   = 64 KB
    f16*   WhT = (f16*)((char*)d_ws + (1 << 16));    // 128*8192*2  = 2 MB
    float* src = (float*)((char*)WhT + (size_t)OUT_F * N * sizeof(f16));
    float* dst = src + N;

    k_prep<<<128, 256, 0, stream>>>(W, WT);
    k_wh<<<N / 32, 256, 0, stream>>>(h, WT, a, WhT, src, dst);
    k_attn<<<N / TI, 512, 0, stream>>>(adj, WhT, src, dst, out);
}